// Round 1
// baseline (396.355 us; speedup 1.0000x reference)
//
#include <hip/hip_runtime.h>
#include <hip/hip_bf16.h>

#define N_NODES 50000
#define N_EDGES 800000
#define FD 128
#define HD 128
#define KTOT 512
#define NTOT 512

typedef __attribute__((ext_vector_type(8))) short short8;
typedef __attribute__((ext_vector_type(8))) __bf16 bf16x8;
typedef __attribute__((ext_vector_type(4))) float f32x4;

__device__ __forceinline__ short f2bf(float f) {
  unsigned u = __builtin_bit_cast(unsigned, f);
  unsigned r = (u + 0x7FFFu + ((u >> 16) & 1u)) >> 16;
  return (short)(r & 0xFFFFu);
}
__device__ __forceinline__ float sigm(float x) { return 1.f / (1.f + __expf(-x)); }
__device__ __forceinline__ float tanh_(float x) { return 2.f / (1.f + __expf(-2.f * x)) - 1.f; }

__global__ void k_zero_cnt(int* __restrict__ cnt) {
  int i = blockIdx.x * 256 + threadIdx.x;
  if (i < N_NODES) cnt[i] = 0;
}

__global__ void k_count(const int* __restrict__ ei, int* __restrict__ cnt) {
  int e = blockIdx.x * 256 + threadIdx.x;
  if (e < N_EDGES) atomicAdd(&cnt[ei[N_EDGES + e]], 1);
}

__global__ void k_scan(const int* __restrict__ cnt, int* __restrict__ off, int* __restrict__ pos) {
  __shared__ int sm[1024];
  int t = threadIdx.x;
  const int chunk = (N_NODES + 1023) / 1024;
  int b = t * chunk, e = min(b + chunk, N_NODES);
  int s = 0;
  for (int i = b; i < e; ++i) s += cnt[i];
  sm[t] = s;
  __syncthreads();
  for (int d = 1; d < 1024; d <<= 1) {
    int v = (t >= d) ? sm[t - d] : 0;
    __syncthreads();
    sm[t] += v;
    __syncthreads();
  }
  int run = (t == 0) ? 0 : sm[t - 1];
  for (int i = b; i < e; ++i) { off[i] = run; pos[i] = run; run += cnt[i]; }
  if (t == 0) off[N_NODES] = sm[1023];
}

__global__ void k_fill(const int* __restrict__ ei, int* __restrict__ pos, int* __restrict__ elist) {
  int e = blockIdx.x * 256 + threadIdx.x;
  if (e < N_EDGES) {
    int d = ei[N_EDGES + e];
    int p = atomicAdd(&pos[d], 1);
    elist[p] = ei[e];
  }
}

// one block (128 threads) per destination node: gather+mean x and h rows, pack A row (bf16)
__global__ void k_agg_pack(const float* __restrict__ x, const float* __restrict__ h,
                           const int* __restrict__ off, const int* __restrict__ elist,
                           short* __restrict__ Apack) {
  int node = blockIdx.x;
  int t = threadIdx.x;  // 0..127
  int b = off[node], e = off[node + 1];
  float ax = 0.f, ah = 0.f;
  for (int j = b; j < e; ++j) {
    int s = elist[j];
    ax += x[s * FD + t];
    ah += h[s * HD + t];
  }
  float inv = 1.f / (float)max(e - b, 1);
  short* row = Apack + (size_t)node * KTOT;
  row[t]       = f2bf(ax * inv);
  row[128 + t] = f2bf(x[node * FD + t]);
  row[256 + t] = f2bf(ah * inv);
  row[384 + t] = f2bf(h[node * HD + t]);
}

// pack B transposed [col'][k], col' = hb*128 + gate*32 + (hid&31), hb = hid>>5
__global__ void k_packB(const float* __restrict__ Wx, const float* __restrict__ Wxr,
                        const float* __restrict__ Wh, const float* __restrict__ Whr,
                        short* __restrict__ BpackT) {
  int gid = blockIdx.x * 256 + threadIdx.x;
  if (gid >= NTOT * KTOT) return;
  int col = gid >> 9;
  int k = gid & 511;
  int hb = col >> 7, rem = col & 127;
  int g = rem >> 5, hlow = rem & 31;
  int hid = hb * 32 + hlow;
  int sel = k >> 7, f = k & 127;
  const float* W = (sel == 0) ? Wx : (sel == 1) ? Wxr : (sel == 2) ? Wh : Whr;
  BpackT[col * KTOT + k] = f2bf(W[(g * 128 + f) * 128 + hid]);
}

// fused GEMM [50000x512]x[512x512] bf16 MFMA + LSTM epilogue
__global__ __launch_bounds__(256) void k_gemm(
    const short* __restrict__ Apack, const short* __restrict__ BpackT,
    const float* __restrict__ c_in, const float* __restrict__ bx, const float* __restrict__ bh,
    const float* __restrict__ fcw,
    float* __restrict__ hnew, float* __restrict__ cnew, float* __restrict__ ypart) {
  __shared__ short As[128 * 40];
  __shared__ short Bs[128 * 40];
  const int tid = threadIdx.x;
  const int wave = tid >> 6, lane = tid & 63;
  const int l15 = lane & 15, lhi = lane >> 4;
  const int rt = blockIdx.x, hb = blockIdx.y;
  const int row0 = rt * 128;

  f32x4 acc[2][8] = {};

  const int srow = tid >> 2;       // 0..63
  const int sch = (tid & 3) * 8;   // 0,8,16,24

  for (int k0 = 0; k0 < KTOT; k0 += 32) {
    __syncthreads();
#pragma unroll
    for (int p = 0; p < 2; ++p) {
      int r = srow + p * 64;
      int gr = row0 + r;
      short8 va;
      if (gr < N_NODES) va = *(const short8*)(Apack + (size_t)gr * KTOT + k0 + sch);
      else va = (short8)0;
      *(short8*)(&As[r * 40 + sch]) = va;
      short8 vb = *(const short8*)(BpackT + (size_t)(hb * 128 + r) * KTOT + k0 + sch);
      *(short8*)(&Bs[r * 40 + sch]) = vb;
    }
    __syncthreads();
    short8 a[2], bfr[8];
#pragma unroll
    for (int m = 0; m < 2; ++m)
      a[m] = *(const short8*)(&As[(wave * 32 + m * 16 + l15) * 40 + lhi * 8]);
#pragma unroll
    for (int n = 0; n < 8; ++n)
      bfr[n] = *(const short8*)(&Bs[(n * 16 + l15) * 40 + lhi * 8]);
#pragma unroll
    for (int m = 0; m < 2; ++m)
#pragma unroll
      for (int n = 0; n < 8; ++n)
        acc[m][n] = __builtin_amdgcn_mfma_f32_16x16x32_bf16(
            __builtin_bit_cast(bf16x8, a[m]), __builtin_bit_cast(bf16x8, bfr[n]),
            acc[m][n], 0, 0, 0);
  }

  // epilogue: acc[m][g*2+n1] reg j -> row = row0 + wave*32 + m*16 + lhi*4 + j,
  // hid = hb*32 + n1*16 + l15, gate g
  const int rbase = row0 + wave * 32 + lhi * 4;
  float yp[2][4] = {};
#pragma unroll
  for (int m = 0; m < 2; ++m) {
#pragma unroll
    for (int n1 = 0; n1 < 2; ++n1) {
      int hid = hb * 32 + n1 * 16 + l15;
      float bi = bx[hid] + bh[hid];
      float bf_ = bx[128 + hid] + bh[128 + hid];
      float bt = bx[256 + hid] + bh[256 + hid];
      float bo = bx[384 + hid] + bh[384 + hid];
      float fw = fcw[hid];
      f32x4 gi = acc[m][0 + n1], gf = acc[m][2 + n1], gt = acc[m][4 + n1], go = acc[m][6 + n1];
#pragma unroll
      for (int j = 0; j < 4; ++j) {
        int r = rbase + m * 16 + j;
        bool ok = r < N_NODES;
        float cv = ok ? c_in[(size_t)r * HD + hid] : 0.f;
        float ig = sigm(gi[j] + bi);
        float fg = sigm(gf[j] + bf_);
        float tg = tanh_(gt[j] + bt);
        float og = sigm(go[j] + bo);
        float cn = fg * cv + ig * tg;
        float hn = og * tanh_(cn);
        if (ok) {
          cnew[(size_t)r * HD + hid] = cn;
          hnew[(size_t)r * HD + hid] = hn;
        }
        yp[m][j] += fmaxf(hn, 0.f) * fw;
      }
    }
  }
#pragma unroll
  for (int m = 0; m < 2; ++m)
#pragma unroll
    for (int j = 0; j < 4; ++j) {
      float v = yp[m][j];
      v += __shfl_xor(v, 1);
      v += __shfl_xor(v, 2);
      v += __shfl_xor(v, 4);
      v += __shfl_xor(v, 8);
      if (l15 == 0) {
        int r = rbase + m * 16 + j;
        if (r < N_NODES) ypart[hb * N_NODES + r] = v;
      }
    }
}

__global__ void k_yfinal(const float* __restrict__ ypart, const float* __restrict__ fcb,
                         float* __restrict__ y) {
  int i = blockIdx.x * 256 + threadIdx.x;
  if (i < N_NODES)
    y[i] = fcb[0] + ypart[i] + ypart[N_NODES + i] + ypart[2 * N_NODES + i] + ypart[3 * N_NODES + i];
}

extern "C" void kernel_launch(void* const* d_in, const int* in_sizes, int n_in,
                              void* d_out, int out_size, void* d_ws, size_t ws_size,
                              hipStream_t stream) {
  const float* x   = (const float*)d_in[0];
  const int*   ei  = (const int*)d_in[1];
  const float* h   = (const float*)d_in[3];
  const float* c   = (const float*)d_in[4];
  const float* Wx  = (const float*)d_in[5];
  const float* Wxr = (const float*)d_in[6];
  const float* bx  = (const float*)d_in[7];
  const float* Wh  = (const float*)d_in[8];
  const float* Whr = (const float*)d_in[9];
  const float* bh  = (const float*)d_in[10];
  const float* fcw = (const float*)d_in[11];
  const float* fcb = (const float*)d_in[12];

  float* y    = (float*)d_out;
  float* hnew = y + N_NODES;
  float* cnew = hnew + (size_t)N_NODES * HD;

  char* w = (char*)d_ws;
  auto carve = [&](size_t bytes) {
    char* p = w;
    w += (bytes + 255) & ~(size_t)255;
    return p;
  };
  int* cnt      = (int*)carve((size_t)N_NODES * 4);
  int* off      = (int*)carve((size_t)(N_NODES + 1) * 4);
  int* pos      = (int*)carve((size_t)N_NODES * 4);
  int* elist    = (int*)carve((size_t)N_EDGES * 4);
  short* Apack  = (short*)carve((size_t)N_NODES * KTOT * 2);
  short* BpackT = (short*)carve((size_t)NTOT * KTOT * 2);
  float* ypart  = (float*)carve((size_t)4 * N_NODES * 4);

  k_zero_cnt<<<(N_NODES + 255) / 256, 256, 0, stream>>>(cnt);
  k_count<<<(N_EDGES + 255) / 256, 256, 0, stream>>>(ei, cnt);
  k_scan<<<1, 1024, 0, stream>>>(cnt, off, pos);
  k_fill<<<(N_EDGES + 255) / 256, 256, 0, stream>>>(ei, pos, elist);
  k_agg_pack<<<N_NODES, 128, 0, stream>>>(x, h, off, elist, Apack);
  k_packB<<<(NTOT * KTOT + 255) / 256, 256, 0, stream>>>(Wx, Wxr, Wh, Whr, BpackT);
  dim3 gg((N_NODES + 127) / 128, 4);
  k_gemm<<<gg, 256, 0, stream>>>(Apack, BpackT, c, bx, bh, fcw, hnew, cnew, ypart);
  k_yfinal<<<(N_NODES + 255) / 256, 256, 0, stream>>>(ypart, fcb, y);
}

// Round 3
// 390.078 us; speedup vs baseline: 1.0161x; 1.0161x over previous
//
#include <hip/hip_runtime.h>
#include <hip/hip_bf16.h>

#define N_NODES 50000
#define N_EDGES 800000
#define FD 128
#define HD 128
#define KTOT 512
#define NTOT 512

typedef __attribute__((ext_vector_type(8))) short short8v;
typedef __attribute__((ext_vector_type(4))) short bfs4;
typedef __attribute__((ext_vector_type(8))) __bf16 bf16x8;
typedef __attribute__((ext_vector_type(4))) float f32x4;

__device__ __forceinline__ short f2bf(float f) {
  unsigned u = __builtin_bit_cast(unsigned, f);
  unsigned r = (u + 0x7FFFu + ((u >> 16) & 1u)) >> 16;
  return (short)(r & 0xFFFFu);
}
__device__ __forceinline__ float sigm(float x) { return 1.f / (1.f + __expf(-x)); }
__device__ __forceinline__ float tanh_(float x) { return 2.f / (1.f + __expf(-2.f * x)) - 1.f; }

// swizzle a logical column c (0..511) within its 64-col block: slot ^= r7
__device__ __forceinline__ int swz_col(int c, int r7) {
  return (c & ~63) | (((((c >> 3) & 7) ^ r7)) << 3) | (c & 7);
}

__device__ __forceinline__ void gload_lds16(const void* g, void* l) {
  __builtin_amdgcn_global_load_lds((const __attribute__((address_space(1))) unsigned int*)g,
                                   (__attribute__((address_space(3))) unsigned int*)l, 16, 0, 0);
}

// merged: zero cnt + pack B transposed+gate-interleaved+swizzled
__global__ void k_pre(const float* __restrict__ Wx, const float* __restrict__ Wxr,
                      const float* __restrict__ Wh, const float* __restrict__ Whr,
                      short* __restrict__ BpackT, int* __restrict__ cnt) {
  int gid = blockIdx.x * 256 + threadIdx.x;
  if (gid < N_NODES) cnt[gid] = 0;
  if (gid >= NTOT * KTOT) return;
  int col = gid >> 9;         // col' = hb*128 + gate*32 + hlow
  int k = gid & 511;
  int hb = col >> 7, rem = col & 127;
  int g = rem >> 5, hlow = rem & 31;
  int hid = hb * 32 + hlow;
  int sel = k >> 7, f = k & 127;
  const float* W = (sel == 0) ? Wx : (sel == 1) ? Wxr : (sel == 2) ? Wh : Whr;
  BpackT[col * KTOT + swz_col(k, col & 7)] = f2bf(W[(g * 128 + f) * 128 + hid]);
}

__global__ void k_count(const int* __restrict__ ei, int* __restrict__ cnt) {
  int e = blockIdx.x * 256 + threadIdx.x;
  if (e < N_EDGES) atomicAdd(&cnt[ei[N_EDGES + e]], 1);
}

__global__ void k_scan(const int* __restrict__ cnt, int* __restrict__ off, int* __restrict__ pos) {
  __shared__ int sm[1024];
  int t = threadIdx.x;
  const int chunk = (N_NODES + 1023) / 1024;
  int b = t * chunk, e = min(b + chunk, N_NODES);
  int s = 0;
  for (int i = b; i < e; ++i) s += cnt[i];
  sm[t] = s;
  __syncthreads();
  for (int d = 1; d < 1024; d <<= 1) {
    int v = (t >= d) ? sm[t - d] : 0;
    __syncthreads();
    sm[t] += v;
    __syncthreads();
  }
  int run = (t == 0) ? 0 : sm[t - 1];
  for (int i = b; i < e; ++i) { off[i] = run; pos[i] = run; run += cnt[i]; }
  if (t == 0) off[N_NODES] = sm[1023];
}

__global__ void k_fill(const int* __restrict__ ei, int* __restrict__ pos, int* __restrict__ elist) {
  int e = blockIdx.x * 256 + threadIdx.x;
  if (e < N_EDGES) {
    int d = ei[N_EDGES + e];
    int p = atomicAdd(&pos[d], 1);
    elist[p] = ei[e];
  }
}

// 4 waves/block, one wave per node. lanes 0-31: x row (float4 each), 32-63: h row.
// One 1KB wave-load per edge; pack A row bf16 pre-swizzled.
__global__ __launch_bounds__(256) void k_agg_pack(const float* __restrict__ x,
                                                  const float* __restrict__ h,
                                                  const int* __restrict__ off,
                                                  const int* __restrict__ elist,
                                                  short* __restrict__ Apack) {
  int tid = threadIdx.x;
  int node = blockIdx.x * 4 + (tid >> 6);
  int lane = tid & 63;
  int half = lane >> 5;   // 0: x, 1: h
  int l5 = lane & 31;
  const float* src = (half ? h : x) + l5 * 4;
  int b = off[node], e = off[node + 1];
  f32x4 acc = {0.f, 0.f, 0.f, 0.f};
  int j = b;
  for (; j + 4 <= e; j += 4) {
    int s0 = elist[j], s1 = elist[j + 1], s2 = elist[j + 2], s3 = elist[j + 3];
    f32x4 v0 = *(const f32x4*)(src + (size_t)s0 * 128);
    f32x4 v1 = *(const f32x4*)(src + (size_t)s1 * 128);
    f32x4 v2 = *(const f32x4*)(src + (size_t)s2 * 128);
    f32x4 v3 = *(const f32x4*)(src + (size_t)s3 * 128);
    acc += v0; acc += v1; acc += v2; acc += v3;
  }
  for (; j < e; ++j) {
    int s = elist[j];
    acc += *(const f32x4*)(src + (size_t)s * 128);
  }
  float inv = 1.f / (float)max(e - b, 1);
  f32x4 self = *(const f32x4*)(src + (size_t)node * 128);
  short* row = Apack + (size_t)node * KTOT;
  int r7 = node & 7;
  int cagg = half * 256 + l5 * 4;   // agg_x at 0..127, agg_h at 256..383
  int cself = cagg + 128;           // x at 128..255, h at 384..511
  bfs4 oa, os;
#pragma unroll
  for (int q = 0; q < 4; ++q) {
    oa[q] = f2bf(acc[q] * inv);
    os[q] = f2bf(self[q]);
  }
  *(bfs4*)(row + swz_col(cagg, r7)) = oa;
  *(bfs4*)(row + swz_col(cself, r7)) = os;
}

// fused GEMM [50000x512]x[512x512] bf16 MFMA + LSTM epilogue.
// BK=64, global_load_lds(16B) staging, linear LDS dest, pre-swizzled source,
// XOR-swizzled ds_read (rule #21: both-sides).
__global__ __launch_bounds__(256) void k_gemm(
    const short* __restrict__ Apack, const short* __restrict__ BpackT,
    const float* __restrict__ c_in, const float* __restrict__ bx, const float* __restrict__ bh,
    const float* __restrict__ fcw,
    float* __restrict__ hnew, float* __restrict__ cnew, float* __restrict__ ypart) {
  __shared__ short As[128 * 64];
  __shared__ short Bs[128 * 64];
  const int tid = threadIdx.x;
  const int wave = tid >> 6, lane = tid & 63;
  const int l15 = lane & 15, lhi = lane >> 4;
  const int rt = blockIdx.x, hb = blockIdx.y;
  const int row0 = rt * 128;

  f32x4 acc[2][8] = {};

  const short* Abase = Apack + (size_t)row0 * KTOT;
  const short* Bbase = BpackT + (size_t)hb * 128 * KTOT;
  const int stg_r = tid >> 3;        // 0..31 (+32 per it)
  const int stg_s = tid & 7;         // 16B slot in 64-col block
  const int ldst = (tid & ~63) * 8;  // wave-uniform part of lds offset (shorts), +it*2048

  for (int k0 = 0; k0 < KTOT; k0 += 64) {
    __syncthreads();
#pragma unroll
    for (int it = 0; it < 4; ++it) {
      int r = stg_r + it * 32;
      gload_lds16(Abase + (size_t)r * KTOT + k0 + stg_s * 8, As + ldst + it * 2048);
      gload_lds16(Bbase + (size_t)r * KTOT + k0 + stg_s * 8, Bs + ldst + it * 2048);
    }
    __syncthreads();
#pragma unroll
    for (int kk = 0; kk < 2; ++kk) {
      short8v a[2], bfr[8];
      const int sl = ((kk << 2) | lhi) ^ (l15 & 7);
#pragma unroll
      for (int m = 0; m < 2; ++m) {
        int ra = wave * 32 + m * 16 + l15;
        a[m] = *(const short8v*)(As + ra * 64 + sl * 8);
      }
#pragma unroll
      for (int n = 0; n < 8; ++n) {
        int rb = n * 16 + l15;
        bfr[n] = *(const short8v*)(Bs + rb * 64 + sl * 8);
      }
#pragma unroll
      for (int m = 0; m < 2; ++m)
#pragma unroll
        for (int n = 0; n < 8; ++n)
          acc[m][n] = __builtin_amdgcn_mfma_f32_16x16x32_bf16(
              __builtin_bit_cast(bf16x8, a[m]), __builtin_bit_cast(bf16x8, bfr[n]),
              acc[m][n], 0, 0, 0);
    }
  }

  // epilogue: acc[m][g*2+n1] reg j -> row = row0 + wave*32 + m*16 + lhi*4 + j,
  // hid = hb*32 + n1*16 + l15, gate g
  const int rbase = row0 + wave * 32 + lhi * 4;
  float yp[2][4] = {};
#pragma unroll
  for (int m = 0; m < 2; ++m) {
#pragma unroll
    for (int n1 = 0; n1 < 2; ++n1) {
      int hid = hb * 32 + n1 * 16 + l15;
      float bi = bx[hid] + bh[hid];
      float bf_ = bx[128 + hid] + bh[128 + hid];
      float bt = bx[256 + hid] + bh[256 + hid];
      float bo = bx[384 + hid] + bh[384 + hid];
      float fw = fcw[hid];
      f32x4 gi = acc[m][0 + n1], gf = acc[m][2 + n1], gt = acc[m][4 + n1], go = acc[m][6 + n1];
#pragma unroll
      for (int j = 0; j < 4; ++j) {
        int r = rbase + m * 16 + j;
        bool ok = r < N_NODES;
        float cv = ok ? c_in[(size_t)r * HD + hid] : 0.f;
        float ig = sigm(gi[j] + bi);
        float fg = sigm(gf[j] + bf_);
        float tg = tanh_(gt[j] + bt);
        float og = sigm(go[j] + bo);
        float cn = fg * cv + ig * tg;
        float hn = og * tanh_(cn);
        if (ok) {
          cnew[(size_t)r * HD + hid] = cn;
          hnew[(size_t)r * HD + hid] = hn;
        }
        yp[m][j] += fmaxf(hn, 0.f) * fw;
      }
    }
  }
#pragma unroll
  for (int m = 0; m < 2; ++m)
#pragma unroll
    for (int j = 0; j < 4; ++j) {
      float v = yp[m][j];
      v += __shfl_xor(v, 1);
      v += __shfl_xor(v, 2);
      v += __shfl_xor(v, 4);
      v += __shfl_xor(v, 8);
      if (l15 == 0) {
        int r = rbase + m * 16 + j;
        if (r < N_NODES) ypart[hb * N_NODES + r] = v;
      }
    }
}

__global__ void k_yfinal(const float* __restrict__ ypart, const float* __restrict__ fcb,
                         float* __restrict__ y) {
  int i = blockIdx.x * 256 + threadIdx.x;
  if (i < N_NODES)
    y[i] = fcb[0] + ypart[i] + ypart[N_NODES + i] + ypart[2 * N_NODES + i] + ypart[3 * N_NODES + i];
}

extern "C" void kernel_launch(void* const* d_in, const int* in_sizes, int n_in,
                              void* d_out, int out_size, void* d_ws, size_t ws_size,
                              hipStream_t stream) {
  const float* x   = (const float*)d_in[0];
  const int*   ei  = (const int*)d_in[1];
  const float* h   = (const float*)d_in[3];
  const float* c   = (const float*)d_in[4];
  const float* Wx  = (const float*)d_in[5];
  const float* Wxr = (const float*)d_in[6];
  const float* bx  = (const float*)d_in[7];
  const float* Wh  = (const float*)d_in[8];
  const float* Whr = (const float*)d_in[9];
  const float* bh  = (const float*)d_in[10];
  const float* fcw = (const float*)d_in[11];
  const float* fcb = (const float*)d_in[12];

  float* y    = (float*)d_out;
  float* hnew = y + N_NODES;
  float* cnew = hnew + (size_t)N_NODES * HD;

  char* w = (char*)d_ws;
  auto carve = [&](size_t bytes) {
    char* p = w;
    w += (bytes + 255) & ~(size_t)255;
    return p;
  };
  int* cnt      = (int*)carve((size_t)N_NODES * 4);
  int* off      = (int*)carve((size_t)(N_NODES + 1) * 4);
  int* pos      = (int*)carve((size_t)N_NODES * 4);
  int* elist    = (int*)carve((size_t)N_EDGES * 4);
  short* Apack  = (short*)carve((size_t)N_NODES * KTOT * 2);
  short* BpackT = (short*)carve((size_t)NTOT * KTOT * 2);   // also absorbs A-tile OOB staging reads
  float* ypart  = (float*)carve((size_t)4 * N_NODES * 4);

  k_pre<<<(NTOT * KTOT + 255) / 256, 256, 0, stream>>>(Wx, Wxr, Wh, Whr, BpackT, cnt);
  k_count<<<(N_EDGES + 255) / 256, 256, 0, stream>>>(ei, cnt);
  k_scan<<<1, 1024, 0, stream>>>(cnt, off, pos);
  k_fill<<<(N_EDGES + 255) / 256, 256, 0, stream>>>(ei, pos, elist);
  k_agg_pack<<<(N_NODES + 3) / 4, 256, 0, stream>>>(x, h, off, elist, Apack);
  dim3 gg((N_NODES + 127) / 128, 4);
  k_gemm<<<gg, 256, 0, stream>>>(Apack, BpackT, c, bx, bh, fcw, hnew, cnew, ypart);
  k_yfinal<<<(N_NODES + 255) / 256, 256, 0, stream>>>(ypart, fcb, y);
}

// Round 4
// 319.887 us; speedup vs baseline: 1.2390x; 1.2194x over previous
//
#include <hip/hip_runtime.h>
#include <hip/hip_bf16.h>

#define N_NODES 50000
#define N_EDGES 800000
#define FD 128
#define HD 128
#define KTOT 512
#define NTOT 512
#define NRT 391          // ceil(50000/128)
#define RT_PER_XCD 49    // ceil(391/8)

typedef __attribute__((ext_vector_type(8))) short short8v;
typedef __attribute__((ext_vector_type(4))) short bfs4;
typedef __attribute__((ext_vector_type(8))) __bf16 bf16x8;
typedef __attribute__((ext_vector_type(4))) float f32x4;

__device__ __forceinline__ short f2bf(float f) {
  unsigned u = __builtin_bit_cast(unsigned, f);
  unsigned r = (u + 0x7FFFu + ((u >> 16) & 1u)) >> 16;
  return (short)(r & 0xFFFFu);
}
__device__ __forceinline__ float bf2f(short s) {
  return __builtin_bit_cast(float, ((unsigned)(unsigned short)s) << 16);
}
__device__ __forceinline__ float sigm(float x) { return 1.f / (1.f + __expf(-x)); }
__device__ __forceinline__ float tanh_(float x) { return 2.f / (1.f + __expf(-2.f * x)) - 1.f; }

// swizzle a logical column c (0..511) within its 64-col block: slot ^= r7
__device__ __forceinline__ int swz_col(int c, int r7) {
  return (c & ~63) | (((((c >> 3) & 7) ^ r7)) << 3) | (c & 7);
}

__device__ __forceinline__ void gload_lds16(const void* g, void* l) {
  __builtin_amdgcn_global_load_lds((const __attribute__((address_space(1))) unsigned int*)g,
                                   (__attribute__((address_space(3))) unsigned int*)l, 16, 0, 0);
}

// merged: zero cnt + pack B transposed+gate-interleaved+swizzled
__global__ void k_pre(const float* __restrict__ Wx, const float* __restrict__ Wxr,
                      const float* __restrict__ Wh, const float* __restrict__ Whr,
                      short* __restrict__ BpackT, int* __restrict__ cnt) {
  int gid = blockIdx.x * 256 + threadIdx.x;
  if (gid < N_NODES) cnt[gid] = 0;
  if (gid >= NTOT * KTOT) return;
  int col = gid >> 9;         // col' = hb*128 + gate*32 + hlow
  int k = gid & 511;
  int hb = col >> 7, rem = col & 127;
  int g = rem >> 5, hlow = rem & 31;
  int hid = hb * 32 + hlow;
  int sel = k >> 7, f = k & 127;
  const float* W = (sel == 0) ? Wx : (sel == 1) ? Wxr : (sel == 2) ? Wh : Whr;
  BpackT[col * KTOT + swz_col(k, col & 7)] = f2bf(W[(g * 128 + f) * 128 + hid]);
}

// write bf16 self-columns of Apack: x -> cols 128..255, h -> cols 384..511 (swizzled)
__global__ void k_tobf(const float* __restrict__ x, const float* __restrict__ h,
                       short* __restrict__ Apack) {
  int gid = blockIdx.x * 256 + threadIdx.x;
  if (gid >= N_NODES * 32) return;
  int half = gid >= N_NODES * 16;       // 0: x, 1: h
  int g2 = gid - half * N_NODES * 16;
  int node = g2 >> 4, s = g2 & 15;      // s: 8-elem slice of the row
  const float* src = (half ? h : x) + (size_t)node * 128 + s * 8;
  f32x4 v0 = *(const f32x4*)(src);
  f32x4 v1 = *(const f32x4*)(src + 4);
  short8v o;
#pragma unroll
  for (int q = 0; q < 4; ++q) { o[q] = f2bf(v0[q]); o[q + 4] = f2bf(v1[q]); }
  int blockbase = 128 + half * 256 + (s >> 3) * 64;
  int slot = (s & 7) ^ (node & 7);
  *(short8v*)(Apack + (size_t)node * KTOT + blockbase + slot * 8) = o;
}

__global__ void k_count(const int* __restrict__ ei, int* __restrict__ cnt) {
  int e = blockIdx.x * 256 + threadIdx.x;
  if (e < N_EDGES) atomicAdd(&cnt[ei[N_EDGES + e]], 1);
}

__global__ void k_scan(const int* __restrict__ cnt, int* __restrict__ off, int* __restrict__ pos) {
  __shared__ int sm[1024];
  int t = threadIdx.x;
  const int chunk = (N_NODES + 1023) / 1024;
  int b = t * chunk, e = min(b + chunk, N_NODES);
  int s = 0;
  for (int i = b; i < e; ++i) s += cnt[i];
  sm[t] = s;
  __syncthreads();
  for (int d = 1; d < 1024; d <<= 1) {
    int v = (t >= d) ? sm[t - d] : 0;
    __syncthreads();
    sm[t] += v;
    __syncthreads();
  }
  int run = (t == 0) ? 0 : sm[t - 1];
  for (int i = b; i < e; ++i) { off[i] = run; pos[i] = run; run += cnt[i]; }
  if (t == 0) off[N_NODES] = sm[1023];
}

__global__ void k_fill(const int* __restrict__ ei, int* __restrict__ pos, int* __restrict__ elist) {
  int e = blockIdx.x * 256 + threadIdx.x;
  if (e < N_EDGES) {
    int d = ei[N_EDGES + e];
    int p = atomicAdd(&pos[d], 1);
    elist[p] = ei[e];
  }
}

// one wave per node, 4 waves/block. Gather bf16 rows from Apack's self-columns
// (2 edges per wave-iteration), mean, write agg columns (swizzled).
// lane groups of 16: grp0: x edge j; grp1: h edge j; grp2: x edge j+1; grp3: h edge j+1.
__global__ __launch_bounds__(256) void k_agg_pack(const int* __restrict__ off,
                                                  const int* __restrict__ elist,
                                                  short* __restrict__ Apack) {
  int tid = threadIdx.x;
  int node = blockIdx.x * 4 + (tid >> 6);
  int lane = tid & 63;
  int grp = lane >> 4, l4 = lane & 15;
  int is_h = grp & 1, epair = grp >> 1;
  int b = off[node], e = off[node + 1];
  const int cb = is_h * 256 + 128 + (l4 >> 3) * 64;  // self-col 64-block base
  const int sl = l4 & 7;
  float acc[8] = {};
  int j = b;
  for (; j + 4 <= e; j += 4) {
    int s0 = elist[j + epair];
    int s1 = elist[j + 2 + epair];
    short8v v0 = *(const short8v*)(Apack + (size_t)s0 * KTOT + cb + ((sl ^ (s0 & 7)) << 3));
    short8v v1 = *(const short8v*)(Apack + (size_t)s1 * KTOT + cb + ((sl ^ (s1 & 7)) << 3));
#pragma unroll
    for (int q = 0; q < 8; ++q) acc[q] += bf2f(v0[q]);
#pragma unroll
    for (int q = 0; q < 8; ++q) acc[q] += bf2f(v1[q]);
  }
  for (; j + 2 <= e; j += 2) {
    int s0 = elist[j + epair];
    short8v v0 = *(const short8v*)(Apack + (size_t)s0 * KTOT + cb + ((sl ^ (s0 & 7)) << 3));
#pragma unroll
    for (int q = 0; q < 8; ++q) acc[q] += bf2f(v0[q]);
  }
  if (j < e && epair == 0) {
    int s0 = elist[j];
    short8v v0 = *(const short8v*)(Apack + (size_t)s0 * KTOT + cb + ((sl ^ (s0 & 7)) << 3));
#pragma unroll
    for (int q = 0; q < 8; ++q) acc[q] += bf2f(v0[q]);
  }
#pragma unroll
  for (int q = 0; q < 8; ++q) acc[q] += __shfl_xor(acc[q], 32);
  if (grp < 2) {
    float inv = 1.f / (float)max(e - b, 1);
    int cagg = is_h * 256 + (l4 >> 3) * 64 + ((sl ^ (node & 7)) << 3);
    short8v o;
#pragma unroll
    for (int q = 0; q < 8; ++q) o[q] = f2bf(acc[q] * inv);
    *(short8v*)(Apack + (size_t)node * KTOT + cagg) = o;
  }
}

// fused GEMM [50000x512]x[512x512] bf16 MFMA + LSTM epilogue.
// BK=64, global_load_lds(16B) staging, linear LDS dest, pre-swizzled source,
// XOR-swizzled ds_read. XCD-grouped work remap: the 4 hb-blocks of one rt
// run consecutively on one XCD so the A-tile is fetched from L3 once.
__global__ __launch_bounds__(256) void k_gemm(
    const short* __restrict__ Apack, const short* __restrict__ BpackT,
    const float* __restrict__ c_in, const float* __restrict__ bx, const float* __restrict__ bh,
    const float* __restrict__ fcw,
    float* __restrict__ hnew, float* __restrict__ cnew, float* __restrict__ ypart) {
  __shared__ short As[128 * 64];
  __shared__ short Bs[128 * 64];
  const int bid = blockIdx.x;
  const int xcd = bid & 7, q = bid >> 3;
  const int rt = xcd * RT_PER_XCD + (q >> 2);
  const int hb = q & 3;
  if (rt >= NRT) return;
  const int tid = threadIdx.x;
  const int wave = tid >> 6, lane = tid & 63;
  const int l15 = lane & 15, lhi = lane >> 4;
  const int row0 = rt * 128;

  f32x4 acc[2][8] = {};

  const short* Abase = Apack + (size_t)row0 * KTOT;
  const short* Bbase = BpackT + (size_t)hb * 128 * KTOT;
  const int stg_r = tid >> 3;        // 0..31 (+32 per it)
  const int stg_s = tid & 7;         // 16B slot in 64-col block
  const int ldst = (tid & ~63) * 8;  // wave-uniform part of lds offset (shorts), +it*2048

  for (int k0 = 0; k0 < KTOT; k0 += 64) {
    __syncthreads();
#pragma unroll
    for (int it = 0; it < 4; ++it) {
      int r = stg_r + it * 32;
      gload_lds16(Abase + (size_t)r * KTOT + k0 + stg_s * 8, As + ldst + it * 2048);
      gload_lds16(Bbase + (size_t)r * KTOT + k0 + stg_s * 8, Bs + ldst + it * 2048);
    }
    __syncthreads();
#pragma unroll
    for (int kk = 0; kk < 2; ++kk) {
      short8v a[2], bfr[8];
      const int sl = ((kk << 2) | lhi) ^ (l15 & 7);
#pragma unroll
      for (int m = 0; m < 2; ++m) {
        int ra = wave * 32 + m * 16 + l15;
        a[m] = *(const short8v*)(As + ra * 64 + sl * 8);
      }
#pragma unroll
      for (int n = 0; n < 8; ++n) {
        int rb = n * 16 + l15;
        bfr[n] = *(const short8v*)(Bs + rb * 64 + sl * 8);
      }
#pragma unroll
      for (int m = 0; m < 2; ++m)
#pragma unroll
        for (int n = 0; n < 8; ++n)
          acc[m][n] = __builtin_amdgcn_mfma_f32_16x16x32_bf16(
              __builtin_bit_cast(bf16x8, a[m]), __builtin_bit_cast(bf16x8, bfr[n]),
              acc[m][n], 0, 0, 0);
    }
  }

  // epilogue: acc[m][g*2+n1] reg j -> row = row0 + wave*32 + m*16 + lhi*4 + j,
  // hid = hb*32 + n1*16 + l15, gate g
  const int rbase = row0 + wave * 32 + lhi * 4;
  float yp[2][4] = {};
#pragma unroll
  for (int m = 0; m < 2; ++m) {
#pragma unroll
    for (int n1 = 0; n1 < 2; ++n1) {
      int hid = hb * 32 + n1 * 16 + l15;
      float bi = bx[hid] + bh[hid];
      float bf_ = bx[128 + hid] + bh[128 + hid];
      float bt = bx[256 + hid] + bh[256 + hid];
      float bo = bx[384 + hid] + bh[384 + hid];
      float fw = fcw[hid];
      f32x4 gi = acc[m][0 + n1], gf = acc[m][2 + n1], gt = acc[m][4 + n1], go = acc[m][6 + n1];
#pragma unroll
      for (int j = 0; j < 4; ++j) {
        int r = rbase + m * 16 + j;
        bool ok = r < N_NODES;
        float cv = ok ? c_in[(size_t)r * HD + hid] : 0.f;
        float ig = sigm(gi[j] + bi);
        float fg = sigm(gf[j] + bf_);
        float tg = tanh_(gt[j] + bt);
        float og = sigm(go[j] + bo);
        float cn = fg * cv + ig * tg;
        float hn = og * tanh_(cn);
        if (ok) {
          cnew[(size_t)r * HD + hid] = cn;
          hnew[(size_t)r * HD + hid] = hn;
        }
        yp[m][j] += fmaxf(hn, 0.f) * fw;
      }
    }
  }
#pragma unroll
  for (int m = 0; m < 2; ++m)
#pragma unroll
    for (int j = 0; j < 4; ++j) {
      float v = yp[m][j];
      v += __shfl_xor(v, 1);
      v += __shfl_xor(v, 2);
      v += __shfl_xor(v, 4);
      v += __shfl_xor(v, 8);
      if (l15 == 0) {
        int r = rbase + m * 16 + j;
        if (r < N_NODES) ypart[hb * N_NODES + r] = v;
      }
    }
}

__global__ void k_yfinal(const float* __restrict__ ypart, const float* __restrict__ fcb,
                         float* __restrict__ y) {
  int i = blockIdx.x * 256 + threadIdx.x;
  if (i < N_NODES)
    y[i] = fcb[0] + ypart[i] + ypart[N_NODES + i] + ypart[2 * N_NODES + i] + ypart[3 * N_NODES + i];
}

extern "C" void kernel_launch(void* const* d_in, const int* in_sizes, int n_in,
                              void* d_out, int out_size, void* d_ws, size_t ws_size,
                              hipStream_t stream) {
  const float* x   = (const float*)d_in[0];
  const int*   ei  = (const int*)d_in[1];
  const float* h   = (const float*)d_in[3];
  const float* c   = (const float*)d_in[4];
  const float* Wx  = (const float*)d_in[5];
  const float* Wxr = (const float*)d_in[6];
  const float* bx  = (const float*)d_in[7];
  const float* Wh  = (const float*)d_in[8];
  const float* Whr = (const float*)d_in[9];
  const float* bh  = (const float*)d_in[10];
  const float* fcw = (const float*)d_in[11];
  const float* fcb = (const float*)d_in[12];

  float* y    = (float*)d_out;
  float* hnew = y + N_NODES;
  float* cnew = hnew + (size_t)N_NODES * HD;

  char* w = (char*)d_ws;
  auto carve = [&](size_t bytes) {
    char* p = w;
    w += (bytes + 255) & ~(size_t)255;
    return p;
  };
  int* cnt      = (int*)carve((size_t)N_NODES * 4);
  int* off      = (int*)carve((size_t)(N_NODES + 1) * 4);
  int* pos      = (int*)carve((size_t)N_NODES * 4);
  int* elist    = (int*)carve((size_t)N_EDGES * 4);
  short* Apack  = (short*)carve((size_t)N_NODES * KTOT * 2);
  short* BpackT = (short*)carve((size_t)NTOT * KTOT * 2);   // also absorbs A-tile OOB staging reads
  float* ypart  = (float*)carve((size_t)4 * N_NODES * 4);

  k_pre<<<(NTOT * KTOT + 255) / 256, 256, 0, stream>>>(Wx, Wxr, Wh, Whr, BpackT, cnt);
  k_tobf<<<(N_NODES * 32 + 255) / 256, 256, 0, stream>>>(x, h, Apack);
  k_count<<<(N_EDGES + 255) / 256, 256, 0, stream>>>(ei, cnt);
  k_scan<<<1, 1024, 0, stream>>>(cnt, off, pos);
  k_fill<<<(N_EDGES + 255) / 256, 256, 0, stream>>>(ei, pos, elist);
  k_agg_pack<<<(N_NODES + 3) / 4, 256, 0, stream>>>(off, elist, Apack);
  dim3 gg(8 * RT_PER_XCD * 4);
  k_gemm<<<gg, 256, 0, stream>>>(Apack, BpackT, c, bx, bh, fcw, hnew, cnew, ypart);
  k_yfinal<<<(N_NODES + 255) / 256, 256, 0, stream>>>(ypart, fcb, y);
}

// Round 6
// 221.332 us; speedup vs baseline: 1.7908x; 1.4453x over previous
//
#include <hip/hip_runtime.h>
#include <hip/hip_bf16.h>

#define N_NODES 50000
#define N_EDGES 800000
#define FD 128
#define HD 128
#define KTOT 512
#define NTOT 512
#define NRT 391          // ceil(50000/128)
#define RT_PER_XCD 49    // ceil(391/8)
#define SCAN_BLK 1024
#define NSCAN ((N_NODES + SCAN_BLK - 1) / SCAN_BLK)   // 49

typedef __attribute__((ext_vector_type(8))) short short8v;
typedef __attribute__((ext_vector_type(8))) __bf16 bf16x8;
typedef __attribute__((ext_vector_type(4))) float f32x4;
typedef __attribute__((ext_vector_type(4))) int i32x4;

__device__ __forceinline__ short f2bf(float f) {
  unsigned u = __builtin_bit_cast(unsigned, f);
  unsigned r = (u + 0x7FFFu + ((u >> 16) & 1u)) >> 16;
  return (short)(r & 0xFFFFu);
}
__device__ __forceinline__ float bf2f(short s) {
  return __builtin_bit_cast(float, ((unsigned)(unsigned short)s) << 16);
}
__device__ __forceinline__ float sigm(float x) { return 1.f / (1.f + __expf(-x)); }
__device__ __forceinline__ float tanh_(float x) { return 2.f / (1.f + __expf(-2.f * x)) - 1.f; }

// swizzle a logical column c (0..511) within its 64-col block: slot ^= r7
__device__ __forceinline__ int swz_col(int c, int r7) {
  return (c & ~63) | (((((c >> 3) & 7) ^ r7)) << 3) | (c & 7);
}

__device__ __forceinline__ void gload_lds16(const void* g, void* l) {
  __builtin_amdgcn_global_load_lds((const __attribute__((address_space(1))) unsigned int*)g,
                                   (__attribute__((address_space(3))) unsigned int*)l, 16, 0, 0);
}

// merged: zero cnt + pack B transposed+gate-interleaved+swizzled
__global__ void k_pre(const float* __restrict__ Wx, const float* __restrict__ Wxr,
                      const float* __restrict__ Wh, const float* __restrict__ Whr,
                      short* __restrict__ BpackT, int* __restrict__ cnt) {
  int gid = blockIdx.x * 256 + threadIdx.x;
  if (gid < N_NODES) cnt[gid] = 0;
  if (gid >= NTOT * KTOT) return;
  int col = gid >> 9;         // col' = hb*128 + gate*32 + hlow
  int k = gid & 511;
  int hb = col >> 7, rem = col & 127;
  int g = rem >> 5, hlow = rem & 31;
  int hid = hb * 32 + hlow;
  int sel = k >> 7, f = k & 127;
  const float* W = (sel == 0) ? Wx : (sel == 1) ? Wxr : (sel == 2) ? Wh : Whr;
  BpackT[col * KTOT + swz_col(k, col & 7)] = f2bf(W[(g * 128 + f) * 128 + hid]);
}

// write bf16 self-columns of Apack: x -> cols 128..255, h -> cols 384..511 (swizzled)
__global__ void k_tobf(const float* __restrict__ x, const float* __restrict__ h,
                       short* __restrict__ Apack) {
  int gid = blockIdx.x * 256 + threadIdx.x;
  if (gid >= N_NODES * 32) return;
  int half = gid >= N_NODES * 16;       // 0: x, 1: h
  int g2 = gid - half * N_NODES * 16;
  int node = g2 >> 4, s = g2 & 15;      // s: 8-elem slice of the row
  const float* src = (half ? h : x) + (size_t)node * 128 + s * 8;
  f32x4 v0 = *(const f32x4*)(src);
  f32x4 v1 = *(const f32x4*)(src + 4);
  short8v o;
#pragma unroll
  for (int q = 0; q < 4; ++q) { o[q] = f2bf(v0[q]); o[q + 4] = f2bf(v1[q]); }
  int blockbase = 128 + half * 256 + (s >> 3) * 64;
  int slot = (s & 7) ^ (node & 7);
  *(short8v*)(Apack + (size_t)node * KTOT + blockbase + slot * 8) = o;
}

__global__ void k_count(const int* __restrict__ ei, int* __restrict__ cnt) {
  int e = blockIdx.x * 256 + threadIdx.x;
  if (e < N_EDGES) atomicAdd(&cnt[ei[N_EDGES + e]], 1);
}

// hierarchical scan: A) per-1024 block sums
__global__ void k_scanA(const int* __restrict__ cnt, int* __restrict__ bsum) {
  int blk = blockIdx.x, t = threadIdx.x;
  int base = blk * SCAN_BLK + t * 4;
  int s = 0;
  if (base + 3 < N_NODES) {
    i32x4 v = *(const i32x4*)(cnt + base);
    s = v.x + v.y + v.z + v.w;
  }
#pragma unroll
  for (int d = 1; d < 64; d <<= 1) s += __shfl_xor(s, d);
  __shared__ int ws[4];
  if ((t & 63) == 0) ws[t >> 6] = s;
  __syncthreads();
  if (t == 0) bsum[blk] = ws[0] + ws[1] + ws[2] + ws[3];
}

// B) one wave scans the 49 block sums (inclusive); writes off[N_NODES]=total
__global__ void k_scanB(const int* __restrict__ bsum, int* __restrict__ boff,
                        int* __restrict__ off) {
  int t = threadIdx.x;
  int v = (t < NSCAN) ? bsum[t] : 0;
#pragma unroll
  for (int d = 1; d < 64; d <<= 1) {
    int u = __shfl_up(v, d);
    if (t >= d) v += u;
  }
  if (t < NSCAN) boff[t] = v;
  if (t == NSCAN - 1) off[N_NODES] = v;
}

// C) block-local exclusive scan + block prefix, vectorized writes
__global__ void k_scanC(const int* __restrict__ cnt, const int* __restrict__ boff,
                        int* __restrict__ off, int* __restrict__ pos) {
  int blk = blockIdx.x, t = threadIdx.x;
  int base = blk * SCAN_BLK + t * 4;
  int c0 = 0, c1 = 0, c2 = 0, c3 = 0;
  bool ok = base + 3 < N_NODES;
  if (ok) {
    i32x4 v = *(const i32x4*)(cnt + base);
    c0 = v.x; c1 = v.y; c2 = v.z; c3 = v.w;
  }
  int s = c0 + c1 + c2 + c3;
  int v = s;
#pragma unroll
  for (int d = 1; d < 64; d <<= 1) {
    int u = __shfl_up(v, d);
    if ((t & 63) >= d) v += u;
  }
  __shared__ int wsum[4];
  if ((t & 63) == 63) wsum[t >> 6] = v;
  __syncthreads();
  int wbase = 0;
  for (int w = 0; w < (t >> 6); ++w) wbase += wsum[w];
  int excl = (blk ? boff[blk - 1] : 0) + wbase + v - s;
  if (ok) {
    i32x4 o = {excl, excl + c0, excl + c0 + c1, excl + c0 + c1 + c2};
    *(i32x4*)(off + base) = o;
    *(i32x4*)(pos + base) = o;
  }
}

__global__ void k_fill(const int* __restrict__ ei, int* __restrict__ pos, int* __restrict__ elist) {
  int e = blockIdx.x * 256 + threadIdx.x;
  if (e < N_EDGES) {
    int d = ei[N_EDGES + e];
    int p = atomicAdd(&pos[d], 1);
    elist[p] = ei[e];
  }
}

// one wave per node, 4 waves/block. Gather bf16 rows from Apack's self-columns
// (2 edges per wave-iteration), mean, write agg columns (swizzled).
__global__ __launch_bounds__(256) void k_agg_pack(const int* __restrict__ off,
                                                  const int* __restrict__ elist,
                                                  short* __restrict__ Apack) {
  int tid = threadIdx.x;
  int node = blockIdx.x * 4 + (tid >> 6);
  int lane = tid & 63;
  int grp = lane >> 4, l4 = lane & 15;
  int is_h = grp & 1, epair = grp >> 1;
  int b = off[node], e = off[node + 1];
  const int cb = is_h * 256 + 128 + (l4 >> 3) * 64;  // self-col 64-block base
  const int sl = l4 & 7;
  float acc[8] = {};
  int j = b;
  for (; j + 4 <= e; j += 4) {
    int s0 = elist[j + epair];
    int s1 = elist[j + 2 + epair];
    short8v v0 = *(const short8v*)(Apack + (size_t)s0 * KTOT + cb + ((sl ^ (s0 & 7)) << 3));
    short8v v1 = *(const short8v*)(Apack + (size_t)s1 * KTOT + cb + ((sl ^ (s1 & 7)) << 3));
#pragma unroll
    for (int q = 0; q < 8; ++q) acc[q] += bf2f(v0[q]);
#pragma unroll
    for (int q = 0; q < 8; ++q) acc[q] += bf2f(v1[q]);
  }
  for (; j + 2 <= e; j += 2) {
    int s0 = elist[j + epair];
    short8v v0 = *(const short8v*)(Apack + (size_t)s0 * KTOT + cb + ((sl ^ (s0 & 7)) << 3));
#pragma unroll
    for (int q = 0; q < 8; ++q) acc[q] += bf2f(v0[q]);
  }
  if (j < e && epair == 0) {
    int s0 = elist[j];
    short8v v0 = *(const short8v*)(Apack + (size_t)s0 * KTOT + cb + ((sl ^ (s0 & 7)) << 3));
#pragma unroll
    for (int q = 0; q < 8; ++q) acc[q] += bf2f(v0[q]);
  }
#pragma unroll
  for (int q = 0; q < 8; ++q) acc[q] += __shfl_xor(acc[q], 32);
  if (grp < 2) {
    float inv = 1.f / (float)max(e - b, 1);
    int cagg = is_h * 256 + (l4 >> 3) * 64 + ((sl ^ (node & 7)) << 3);
    short8v o;
#pragma unroll
    for (int q = 0; q < 8; ++q) o[q] = f2bf(acc[q] * inv);
    *(short8v*)(Apack + (size_t)node * KTOT + cagg) = o;
  }
}

// fused GEMM [50000x512]x[512x512] bf16 MFMA + LSTM epilogue.
__global__ __launch_bounds__(256) void k_gemm(
    const short* __restrict__ Apack, const short* __restrict__ BpackT,
    const float* __restrict__ c_in, const float* __restrict__ bx, const float* __restrict__ bh,
    const float* __restrict__ fcw,
    float* __restrict__ hnew, float* __restrict__ cnew, float* __restrict__ ypart) {
  __shared__ short As[128 * 64];
  __shared__ short Bs[128 * 64];
  const int bid = blockIdx.x;
  const int xcd = bid & 7, q = bid >> 3;
  const int rt = xcd * RT_PER_XCD + (q >> 2);
  const int hb = q & 3;
  if (rt >= NRT) return;
  const int tid = threadIdx.x;
  const int wave = tid >> 6, lane = tid & 63;
  const int l15 = lane & 15, lhi = lane >> 4;
  const int row0 = rt * 128;

  f32x4 acc[2][8] = {};

  const short* Abase = Apack + (size_t)row0 * KTOT;
  const short* Bbase = BpackT + (size_t)hb * 128 * KTOT;
  const int stg_r = tid >> 3;        // 0..31 (+32 per it)
  const int stg_s = tid & 7;         // 16B slot in 64-col block
  const int ldst = (tid & ~63) * 8;  // wave-uniform part of lds offset (shorts), +it*2048

  for (int k0 = 0; k0 < KTOT; k0 += 64) {
    __syncthreads();
#pragma unroll
    for (int it = 0; it < 4; ++it) {
      int r = stg_r + it * 32;
      gload_lds16(Abase + (size_t)r * KTOT + k0 + stg_s * 8, As + ldst + it * 2048);
      gload_lds16(Bbase + (size_t)r * KTOT + k0 + stg_s * 8, Bs + ldst + it * 2048);
    }
    __syncthreads();
#pragma unroll
    for (int kk = 0; kk < 2; ++kk) {
      short8v a[2], bfr[8];
      const int sl = ((kk << 2) | lhi) ^ (l15 & 7);
#pragma unroll
      for (int m = 0; m < 2; ++m) {
        int ra = wave * 32 + m * 16 + l15;
        a[m] = *(const short8v*)(As + ra * 64 + sl * 8);
      }
#pragma unroll
      for (int n = 0; n < 8; ++n) {
        int rb = n * 16 + l15;
        bfr[n] = *(const short8v*)(Bs + rb * 64 + sl * 8);
      }
#pragma unroll
      for (int m = 0; m < 2; ++m)
#pragma unroll
        for (int n = 0; n < 8; ++n)
          acc[m][n] = __builtin_amdgcn_mfma_f32_16x16x32_bf16(
              __builtin_bit_cast(bf16x8, a[m]), __builtin_bit_cast(bf16x8, bfr[n]),
              acc[m][n], 0, 0, 0);
    }
  }

  const int rbase = row0 + wave * 32 + lhi * 4;
  float yp[2][4] = {};
#pragma unroll
  for (int m = 0; m < 2; ++m) {
#pragma unroll
    for (int n1 = 0; n1 < 2; ++n1) {
      int hid = hb * 32 + n1 * 16 + l15;
      float bi = bx[hid] + bh[hid];
      float bf_ = bx[128 + hid] + bh[128 + hid];
      float bt = bx[256 + hid] + bh[256 + hid];
      float bo = bx[384 + hid] + bh[384 + hid];
      float fw = fcw[hid];
      f32x4 gi = acc[m][0 + n1], gf = acc[m][2 + n1], gt = acc[m][4 + n1], go = acc[m][6 + n1];
#pragma unroll
      for (int j = 0; j < 4; ++j) {
        int r = rbase + m * 16 + j;
        bool ok = r < N_NODES;
        float cv = ok ? c_in[(size_t)r * HD + hid] : 0.f;
        float ig = sigm(gi[j] + bi);
        float fg = sigm(gf[j] + bf_);
        float tg = tanh_(gt[j] + bt);
        float og = sigm(go[j] + bo);
        float cn = fg * cv + ig * tg;
        float hn = og * tanh_(cn);
        if (ok) {
          cnew[(size_t)r * HD + hid] = cn;
          hnew[(size_t)r * HD + hid] = hn;
        }
        yp[m][j] += fmaxf(hn, 0.f) * fw;
      }
    }
  }
#pragma unroll
  for (int m = 0; m < 2; ++m)
#pragma unroll
    for (int j = 0; j < 4; ++j) {
      float v = yp[m][j];
      v += __shfl_xor(v, 1);
      v += __shfl_xor(v, 2);
      v += __shfl_xor(v, 4);
      v += __shfl_xor(v, 8);
      if (l15 == 0) {
        int r = rbase + m * 16 + j;
        if (r < N_NODES) ypart[hb * N_NODES + r] = v;
      }
    }
}

__global__ void k_yfinal(const float* __restrict__ ypart, const float* __restrict__ fcb,
                         float* __restrict__ y) {
  int i = blockIdx.x * 256 + threadIdx.x;
  if (i < N_NODES)
    y[i] = fcb[0] + ypart[i] + ypart[N_NODES + i] + ypart[2 * N_NODES + i] + ypart[3 * N_NODES + i];
}

extern "C" void kernel_launch(void* const* d_in, const int* in_sizes, int n_in,
                              void* d_out, int out_size, void* d_ws, size_t ws_size,
                              hipStream_t stream) {
  const float* x   = (const float*)d_in[0];
  const int*   ei  = (const int*)d_in[1];
  const float* h   = (const float*)d_in[3];
  const float* c   = (const float*)d_in[4];
  const float* Wx  = (const float*)d_in[5];
  const float* Wxr = (const float*)d_in[6];
  const float* bx  = (const float*)d_in[7];
  const float* Wh  = (const float*)d_in[8];
  const float* Whr = (const float*)d_in[9];
  const float* bh  = (const float*)d_in[10];
  const float* fcw = (const float*)d_in[11];
  const float* fcb = (const float*)d_in[12];

  float* y    = (float*)d_out;
  float* hnew = y + N_NODES;
  float* cnew = hnew + (size_t)N_NODES * HD;

  char* w = (char*)d_ws;
  auto carve = [&](size_t bytes) {
    char* p = w;
    w += (bytes + 255) & ~(size_t)255;
    return p;
  };
  // EXACT round-4 footprint (proven to fit ws_size). bsum/boff overlay ypart:
  // their lifetime (scan phase) ends before k_gemm writes ypart.
  int* cnt      = (int*)carve((size_t)N_NODES * 4);
  int* off      = (int*)carve((size_t)(N_NODES + 1) * 4);
  int* pos      = (int*)carve((size_t)N_NODES * 4);
  int* elist    = (int*)carve((size_t)N_EDGES * 4);
  short* Apack  = (short*)carve((size_t)N_NODES * KTOT * 2);
  short* BpackT = (short*)carve((size_t)NTOT * KTOT * 2);   // also absorbs A-tile OOB staging reads
  float* ypart  = (float*)carve((size_t)4 * N_NODES * 4);
  int* bsum     = (int*)ypart;        // 49 ints, dead before k_gemm
  int* boff     = ((int*)ypart) + 64; // 49 ints, dead before k_gemm

  k_pre<<<(NTOT * KTOT + 255) / 256, 256, 0, stream>>>(Wx, Wxr, Wh, Whr, BpackT, cnt);
  k_tobf<<<(N_NODES * 32 + 255) / 256, 256, 0, stream>>>(x, h, Apack);
  k_count<<<(N_EDGES + 255) / 256, 256, 0, stream>>>(ei, cnt);
  k_scanA<<<NSCAN, 256, 0, stream>>>(cnt, bsum);
  k_scanB<<<1, 64, 0, stream>>>(bsum, boff, off);
  k_scanC<<<NSCAN, 256, 0, stream>>>(cnt, boff, off, pos);
  k_fill<<<(N_EDGES + 255) / 256, 256, 0, stream>>>(ei, pos, elist);
  k_agg_pack<<<(N_NODES + 3) / 4, 256, 0, stream>>>(off, elist, Apack);
  dim3 gg(8 * RT_PER_XCD * 4);
  k_gemm<<<gg, 256, 0, stream>>>(Apack, BpackT, c, bx, bh, fcw, hnew, cnew, ypart);
  k_yfinal<<<(N_NODES + 255) / 256, 256, 0, stream>>>(ypart, fcb, y);
}

// Round 7
// 216.487 us; speedup vs baseline: 1.8309x; 1.0224x over previous
//
#include <hip/hip_runtime.h>
#include <hip/hip_bf16.h>

#define N_NODES 50000
#define N_EDGES 800000
#define FD 128
#define HD 128
#define KTOT 512
#define NTOT 512
#define NRT 391          // ceil(50000/128)
#define RT_PER_XCD 49    // ceil(391/8)
#define SCAN_BLK 1024
#define NSCAN ((N_NODES + SCAN_BLK - 1) / SCAN_BLK)   // 49

typedef __attribute__((ext_vector_type(8))) short short8v;
typedef __attribute__((ext_vector_type(8))) __bf16 bf16x8;
typedef __attribute__((ext_vector_type(4))) float f32x4;
typedef __attribute__((ext_vector_type(4))) int i32x4;

__device__ __forceinline__ short f2bf(float f) {
  unsigned u = __builtin_bit_cast(unsigned, f);
  unsigned r = (u + 0x7FFFu + ((u >> 16) & 1u)) >> 16;
  return (short)(r & 0xFFFFu);
}
__device__ __forceinline__ float bf2f(short s) {
  return __builtin_bit_cast(float, ((unsigned)(unsigned short)s) << 16);
}
// fast gate math: v_exp_f32 (2^x) + v_rcp_f32, ~1ulp — far below bf16 noise
__device__ __forceinline__ float sigm(float x) {
  return __builtin_amdgcn_rcpf(1.f + __builtin_amdgcn_exp2f(-1.44269504f * x));
}
__device__ __forceinline__ float tanh_(float x) {
  return 1.f - 2.f * __builtin_amdgcn_rcpf(1.f + __builtin_amdgcn_exp2f(2.88539009f * x));
}

// swizzle a logical column c (0..511) within its 64-col block: slot ^= r7
__device__ __forceinline__ int swz_col(int c, int r7) {
  return (c & ~63) | (((((c >> 3) & 7) ^ r7)) << 3) | (c & 7);
}

__device__ __forceinline__ void gload_lds16(const void* g, void* l) {
  __builtin_amdgcn_global_load_lds((const __attribute__((address_space(1))) unsigned int*)g,
                                   (__attribute__((address_space(3))) unsigned int*)l, 16, 0, 0);
}

// merged: zero cnt + pack B transposed+gate-interleaved+swizzled
__global__ void k_pre(const float* __restrict__ Wx, const float* __restrict__ Wxr,
                      const float* __restrict__ Wh, const float* __restrict__ Whr,
                      short* __restrict__ BpackT, int* __restrict__ cnt) {
  int gid = blockIdx.x * 256 + threadIdx.x;
  if (gid < N_NODES) cnt[gid] = 0;
  if (gid >= NTOT * KTOT) return;
  int col = gid >> 9;         // col' = hb*128 + gate*32 + hlow
  int k = gid & 511;
  int hb = col >> 7, rem = col & 127;
  int g = rem >> 5, hlow = rem & 31;
  int hid = hb * 32 + hlow;
  int sel = k >> 7, f = k & 127;
  const float* W = (sel == 0) ? Wx : (sel == 1) ? Wxr : (sel == 2) ? Wh : Whr;
  BpackT[col * KTOT + swz_col(k, col & 7)] = f2bf(W[(g * 128 + f) * 128 + hid]);
}

// write bf16 self-columns of Apack: x -> cols 128..255, h -> cols 384..511 (swizzled)
__global__ void k_tobf(const float* __restrict__ x, const float* __restrict__ h,
                       short* __restrict__ Apack) {
  int gid = blockIdx.x * 256 + threadIdx.x;
  if (gid >= N_NODES * 32) return;
  int half = gid >= N_NODES * 16;       // 0: x, 1: h
  int g2 = gid - half * N_NODES * 16;
  int node = g2 >> 4, s = g2 & 15;      // s: 8-elem slice of the row
  const float* src = (half ? h : x) + (size_t)node * 128 + s * 8;
  f32x4 v0 = *(const f32x4*)(src);
  f32x4 v1 = *(const f32x4*)(src + 4);
  short8v o;
#pragma unroll
  for (int q = 0; q < 4; ++q) { o[q] = f2bf(v0[q]); o[q + 4] = f2bf(v1[q]); }
  int blockbase = 128 + half * 256 + (s >> 3) * 64;
  int slot = (s & 7) ^ (node & 7);
  *(short8v*)(Apack + (size_t)node * KTOT + blockbase + slot * 8) = o;
}

__global__ void k_count(const int* __restrict__ ei, int* __restrict__ cnt) {
  int e = blockIdx.x * 256 + threadIdx.x;
  if (e < N_EDGES) atomicAdd(&cnt[ei[N_EDGES + e]], 1);
}

// hierarchical scan: A) per-1024 block sums
__global__ void k_scanA(const int* __restrict__ cnt, int* __restrict__ bsum) {
  int blk = blockIdx.x, t = threadIdx.x;
  int base = blk * SCAN_BLK + t * 4;
  int s = 0;
  if (base + 3 < N_NODES) {
    i32x4 v = *(const i32x4*)(cnt + base);
    s = v.x + v.y + v.z + v.w;
  }
#pragma unroll
  for (int d = 1; d < 64; d <<= 1) s += __shfl_xor(s, d);
  __shared__ int ws[4];
  if ((t & 63) == 0) ws[t >> 6] = s;
  __syncthreads();
  if (t == 0) bsum[blk] = ws[0] + ws[1] + ws[2] + ws[3];
}

// B) one wave scans the 49 block sums (inclusive); writes off[N_NODES]=total
__global__ void k_scanB(const int* __restrict__ bsum, int* __restrict__ boff,
                        int* __restrict__ off) {
  int t = threadIdx.x;
  int v = (t < NSCAN) ? bsum[t] : 0;
#pragma unroll
  for (int d = 1; d < 64; d <<= 1) {
    int u = __shfl_up(v, d);
    if (t >= d) v += u;
  }
  if (t < NSCAN) boff[t] = v;
  if (t == NSCAN - 1) off[N_NODES] = v;
}

// C) block-local exclusive scan + block prefix, vectorized writes
__global__ void k_scanC(const int* __restrict__ cnt, const int* __restrict__ boff,
                        int* __restrict__ off, int* __restrict__ pos) {
  int blk = blockIdx.x, t = threadIdx.x;
  int base = blk * SCAN_BLK + t * 4;
  int c0 = 0, c1 = 0, c2 = 0, c3 = 0;
  bool ok = base + 3 < N_NODES;
  if (ok) {
    i32x4 v = *(const i32x4*)(cnt + base);
    c0 = v.x; c1 = v.y; c2 = v.z; c3 = v.w;
  }
  int s = c0 + c1 + c2 + c3;
  int v = s;
#pragma unroll
  for (int d = 1; d < 64; d <<= 1) {
    int u = __shfl_up(v, d);
    if ((t & 63) >= d) v += u;
  }
  __shared__ int wsum[4];
  if ((t & 63) == 63) wsum[t >> 6] = v;
  __syncthreads();
  int wbase = 0;
  for (int w = 0; w < (t >> 6); ++w) wbase += wsum[w];
  int excl = (blk ? boff[blk - 1] : 0) + wbase + v - s;
  if (ok) {
    i32x4 o = {excl, excl + c0, excl + c0 + c1, excl + c0 + c1 + c2};
    *(i32x4*)(off + base) = o;
    *(i32x4*)(pos + base) = o;
  }
}

__global__ void k_fill(const int* __restrict__ ei, int* __restrict__ pos, int* __restrict__ elist) {
  int e = blockIdx.x * 256 + threadIdx.x;
  if (e < N_EDGES) {
    int d = ei[N_EDGES + e];
    int p = atomicAdd(&pos[d], 1);
    elist[p] = ei[e];
  }
}

// one wave per node, 4 waves/block. Gather bf16 rows from Apack's self-columns
// (2 edges per wave-iteration), mean, write agg columns (swizzled).
__global__ __launch_bounds__(256) void k_agg_pack(const int* __restrict__ off,
                                                  const int* __restrict__ elist,
                                                  short* __restrict__ Apack) {
  int tid = threadIdx.x;
  int node = blockIdx.x * 4 + (tid >> 6);
  int lane = tid & 63;
  int grp = lane >> 4, l4 = lane & 15;
  int is_h = grp & 1, epair = grp >> 1;
  int b = off[node], e = off[node + 1];
  const int cb = is_h * 256 + 128 + (l4 >> 3) * 64;  // self-col 64-block base
  const int sl = l4 & 7;
  float acc[8] = {};
  int j = b;
  for (; j + 4 <= e; j += 4) {
    int s0 = elist[j + epair];
    int s1 = elist[j + 2 + epair];
    short8v v0 = *(const short8v*)(Apack + (size_t)s0 * KTOT + cb + ((sl ^ (s0 & 7)) << 3));
    short8v v1 = *(const short8v*)(Apack + (size_t)s1 * KTOT + cb + ((sl ^ (s1 & 7)) << 3));
#pragma unroll
    for (int q = 0; q < 8; ++q) acc[q] += bf2f(v0[q]);
#pragma unroll
    for (int q = 0; q < 8; ++q) acc[q] += bf2f(v1[q]);
  }
  for (; j + 2 <= e; j += 2) {
    int s0 = elist[j + epair];
    short8v v0 = *(const short8v*)(Apack + (size_t)s0 * KTOT + cb + ((sl ^ (s0 & 7)) << 3));
#pragma unroll
    for (int q = 0; q < 8; ++q) acc[q] += bf2f(v0[q]);
  }
  if (j < e && epair == 0) {
    int s0 = elist[j];
    short8v v0 = *(const short8v*)(Apack + (size_t)s0 * KTOT + cb + ((sl ^ (s0 & 7)) << 3));
#pragma unroll
    for (int q = 0; q < 8; ++q) acc[q] += bf2f(v0[q]);
  }
#pragma unroll
  for (int q = 0; q < 8; ++q) acc[q] += __shfl_xor(acc[q], 32);
  if (grp < 2) {
    float inv = 1.f / (float)max(e - b, 1);
    int cagg = is_h * 256 + (l4 >> 3) * 64 + ((sl ^ (node & 7)) << 3);
    short8v o;
#pragma unroll
    for (int q = 0; q < 8; ++q) o[q] = f2bf(acc[q] * inv);
    *(short8v*)(Apack + (size_t)node * KTOT + cagg) = o;
  }
}

// fused GEMM [50000x512]x[512x512] bf16 MFMA + LSTM epilogue.
__global__ __launch_bounds__(256) void k_gemm(
    const short* __restrict__ Apack, const short* __restrict__ BpackT,
    const float* __restrict__ c_in, const float* __restrict__ bx, const float* __restrict__ bh,
    const float* __restrict__ fcw,
    float* __restrict__ hnew, float* __restrict__ cnew, float* __restrict__ ypart) {
  __shared__ short As[128 * 64];
  __shared__ short Bs[128 * 64];
  const int bid = blockIdx.x;
  const int xcd = bid & 7, q = bid >> 3;
  const int rt = xcd * RT_PER_XCD + (q >> 2);
  const int hb = q & 3;
  if (rt >= NRT) return;
  const int tid = threadIdx.x;
  const int wave = tid >> 6, lane = tid & 63;
  const int l15 = lane & 15, lhi = lane >> 4;
  const int row0 = rt * 128;

  f32x4 acc[2][8] = {};

  const short* Abase = Apack + (size_t)row0 * KTOT;
  const short* Bbase = BpackT + (size_t)hb * 128 * KTOT;
  const int stg_r = tid >> 3;        // 0..31 (+32 per it)
  const int stg_s = tid & 7;         // 16B slot in 64-col block
  const int ldst = (tid & ~63) * 8;  // wave-uniform part of lds offset (shorts), +it*2048

  for (int k0 = 0; k0 < KTOT; k0 += 64) {
    __syncthreads();
#pragma unroll
    for (int it = 0; it < 4; ++it) {
      int r = stg_r + it * 32;
      gload_lds16(Abase + (size_t)r * KTOT + k0 + stg_s * 8, As + ldst + it * 2048);
      gload_lds16(Bbase + (size_t)r * KTOT + k0 + stg_s * 8, Bs + ldst + it * 2048);
    }
    __syncthreads();
#pragma unroll
    for (int kk = 0; kk < 2; ++kk) {
      short8v a[2], bfr[8];
      const int sl = ((kk << 2) | lhi) ^ (l15 & 7);
#pragma unroll
      for (int m = 0; m < 2; ++m) {
        int ra = wave * 32 + m * 16 + l15;
        a[m] = *(const short8v*)(As + ra * 64 + sl * 8);
      }
#pragma unroll
      for (int n = 0; n < 8; ++n) {
        int rb = n * 16 + l15;
        bfr[n] = *(const short8v*)(Bs + rb * 64 + sl * 8);
      }
#pragma unroll
      for (int m = 0; m < 2; ++m)
#pragma unroll
        for (int n = 0; n < 8; ++n)
          acc[m][n] = __builtin_amdgcn_mfma_f32_16x16x32_bf16(
              __builtin_bit_cast(bf16x8, a[m]), __builtin_bit_cast(bf16x8, bfr[n]),
              acc[m][n], 0, 0, 0);
    }
  }

  const int rbase = row0 + wave * 32 + lhi * 4;
  float yp[2][4] = {};
#pragma unroll
  for (int m = 0; m < 2; ++m) {
#pragma unroll
    for (int n1 = 0; n1 < 2; ++n1) {
      int hid = hb * 32 + n1 * 16 + l15;
      float bi = bx[hid] + bh[hid];
      float bf_ = bx[128 + hid] + bh[128 + hid];
      float bt = bx[256 + hid] + bh[256 + hid];
      float bo = bx[384 + hid] + bh[384 + hid];
      float fw = fcw[hid];
      f32x4 gi = acc[m][0 + n1], gf = acc[m][2 + n1], gt = acc[m][4 + n1], go = acc[m][6 + n1];
#pragma unroll
      for (int j = 0; j < 4; ++j) {
        int r = rbase + m * 16 + j;
        bool ok = r < N_NODES;
        float cv = ok ? c_in[(size_t)r * HD + hid] : 0.f;
        float ig = sigm(gi[j] + bi);
        float fg = sigm(gf[j] + bf_);
        float tg = tanh_(gt[j] + bt);
        float og = sigm(go[j] + bo);
        float cn = fg * cv + ig * tg;
        float hn = og * tanh_(cn);
        if (ok) {
          cnew[(size_t)r * HD + hid] = cn;
          hnew[(size_t)r * HD + hid] = hn;
        }
        yp[m][j] += fmaxf(hn, 0.f) * fw;
      }
    }
  }
#pragma unroll
  for (int m = 0; m < 2; ++m)
#pragma unroll
    for (int j = 0; j < 4; ++j) {
      float v = yp[m][j];
      v += __shfl_xor(v, 1);
      v += __shfl_xor(v, 2);
      v += __shfl_xor(v, 4);
      v += __shfl_xor(v, 8);
      if (l15 == 0) {
        int r = rbase + m * 16 + j;
        if (r < N_NODES) ypart[hb * N_NODES + r] = v;
      }
    }
}

__global__ void k_yfinal(const float* __restrict__ ypart, const float* __restrict__ fcb,
                         float* __restrict__ y) {
  int i = blockIdx.x * 256 + threadIdx.x;
  if (i < N_NODES)
    y[i] = fcb[0] + ypart[i] + ypart[N_NODES + i] + ypart[2 * N_NODES + i] + ypart[3 * N_NODES + i];
}

extern "C" void kernel_launch(void* const* d_in, const int* in_sizes, int n_in,
                              void* d_out, int out_size, void* d_ws, size_t ws_size,
                              hipStream_t stream) {
  const float* x   = (const float*)d_in[0];
  const int*   ei  = (const int*)d_in[1];
  const float* h   = (const float*)d_in[3];
  const float* c   = (const float*)d_in[4];
  const float* Wx  = (const float*)d_in[5];
  const float* Wxr = (const float*)d_in[6];
  const float* bx  = (const float*)d_in[7];
  const float* Wh  = (const float*)d_in[8];
  const float* Whr = (const float*)d_in[9];
  const float* bh  = (const float*)d_in[10];
  const float* fcw = (const float*)d_in[11];
  const float* fcb = (const float*)d_in[12];

  float* y    = (float*)d_out;
  float* hnew = y + N_NODES;
  float* cnew = hnew + (size_t)N_NODES * HD;

  char* w = (char*)d_ws;
  auto carve = [&](size_t bytes) {
    char* p = w;
    w += (bytes + 255) & ~(size_t)255;
    return p;
  };
  // EXACT round-4 footprint (proven to fit ws_size). bsum/boff overlay ypart:
  // their lifetime (scan phase) ends before k_gemm writes ypart.
  int* cnt      = (int*)carve((size_t)N_NODES * 4);
  int* off      = (int*)carve((size_t)(N_NODES + 1) * 4);
  int* pos      = (int*)carve((size_t)N_NODES * 4);
  int* elist    = (int*)carve((size_t)N_EDGES * 4);
  short* Apack  = (short*)carve((size_t)N_NODES * KTOT * 2);
  short* BpackT = (short*)carve((size_t)NTOT * KTOT * 2);   // also absorbs A-tile OOB staging reads
  float* ypart  = (float*)carve((size_t)4 * N_NODES * 4);
  int* bsum     = (int*)ypart;        // 49 ints, dead before k_gemm
  int* boff     = ((int*)ypart) + 64; // 49 ints, dead before k_gemm

  k_pre<<<(NTOT * KTOT + 255) / 256, 256, 0, stream>>>(Wx, Wxr, Wh, Whr, BpackT, cnt);
  k_tobf<<<(N_NODES * 32 + 255) / 256, 256, 0, stream>>>(x, h, Apack);
  k_count<<<(N_EDGES + 255) / 256, 256, 0, stream>>>(ei, cnt);
  k_scanA<<<NSCAN, 256, 0, stream>>>(cnt, bsum);
  k_scanB<<<1, 64, 0, stream>>>(bsum, boff, off);
  k_scanC<<<NSCAN, 256, 0, stream>>>(cnt, boff, off, pos);
  k_fill<<<(N_EDGES + 255) / 256, 256, 0, stream>>>(ei, pos, elist);
  k_agg_pack<<<(N_NODES + 3) / 4, 256, 0, stream>>>(off, elist, Apack);
  dim3 gg(8 * RT_PER_XCD * 4);
  k_gemm<<<gg, 256, 0, stream>>>(Apack, BpackT, c, bx, bh, fcw, hnew, cnew, ypart);
  k_yfinal<<<(N_NODES + 255) / 256, 256, 0, stream>>>(ypart, fcb, y);
}